// Round 8
// baseline (408.846 us; speedup 1.0000x reference)
//
#include <hip/hip_runtime.h>
#include <hip/hip_bf16.h>
#include <math.h>

#define NTOK 4096
#define DIMSZ 1024
#define HID 4096
#define NE 8
#define RT_MAX 40   // max sum over experts of ceil(count/128) is 39; pad to 40

typedef unsigned short u16;
typedef unsigned int u32;
typedef __attribute__((ext_vector_type(8))) short bf16x8;
typedef __attribute__((ext_vector_type(4))) float f32x4;

static __device__ __forceinline__ u16 f2bf(float f) {
    u32 u = __float_as_uint(f);
    u32 r = u + 0x7fffu + ((u >> 16) & 1u);   // round-to-nearest-even
    return (u16)(r >> 16);
}

static __device__ __forceinline__ u32 pk2bf(float lo, float hi) {
    __hip_bfloat162 h = __float22bfloat162_rn(make_float2(lo, hi));
    return *(u32*)&h;
}

// ---------------- init: zero counts + cursor ----------------
__global__ void k_init(int* counts, int* cursor) {
    if (threadIdx.x < NE) { counts[threadIdx.x] = 0; cursor[threadIdx.x] = 0; }
}

// ---------------- zero d_out (for GEMM2 K-split atomics) ----------------
__global__ void k_zero(float* p) {
    int i = blockIdx.x * 1024 + threadIdx.x * 4;
    *(float4*)(p + i) = make_float4(0.f, 0.f, 0.f, 0.f);
}

// ---------------- router: fp32 argmax over 8 experts ----------------
__global__ __launch_bounds__(256) void k_router(const float* __restrict__ x,
                                                const float* __restrict__ Wg,
                                                int* __restrict__ ids,
                                                int* __restrict__ counts) {
    int wave = threadIdx.x >> 6;
    int lane = threadIdx.x & 63;
    int t = blockIdx.x * 4 + wave;

    const float4* xr = (const float4*)(x + (size_t)t * DIMSZ);
    float4 xv[4];
#pragma unroll
    for (int j = 0; j < 4; j++) xv[j] = xr[j * 64 + lane];

    float s[NE];
#pragma unroll
    for (int e = 0; e < NE; e++) {
        const float4* wr = (const float4*)(Wg + (size_t)e * DIMSZ);
        float p = 0.f;
#pragma unroll
        for (int j = 0; j < 4; j++) {
            float4 w = wr[j * 64 + lane];
            p += xv[j].x * w.x + xv[j].y * w.y + xv[j].z * w.z + xv[j].w * w.w;
        }
#pragma unroll
        for (int m = 32; m >= 1; m >>= 1) p += __shfl_xor(p, m, 64);
        s[e] = p;
    }
    if (lane == 0) {
        int best = 0;
#pragma unroll
        for (int e = 1; e < NE; e++) if (s[e] > s[best]) best = e;  // first-max tiebreak
        ids[t] = best;
        atomicAdd(&counts[best], 1);
    }
}

// ---------------- scan: exclusive prefix over 8 counts ----------------
__global__ void k_scan(const int* __restrict__ counts, int* __restrict__ offs) {
    if (threadIdx.x == 0) {
        int a = 0;
        for (int e = 0; e < NE; e++) { offs[e] = a; a += counts[e]; }
    }
}

// ---------------- gather: build perm + bf16-convert x into grouped Xg ----------------
__global__ __launch_bounds__(256) void k_gather(const float* __restrict__ x,
                                                const int* __restrict__ ids,
                                                const int* __restrict__ offs,
                                                int* __restrict__ cursor,
                                                int* __restrict__ perm,
                                                u16* __restrict__ Xg) {
    int t = blockIdx.x;
    __shared__ int sp;
    if (threadIdx.x == 0) {
        int e = ids[t];
        int p = offs[e] + atomicAdd(&cursor[e], 1);
        perm[p] = t;
        sp = p;
    }
    __syncthreads();
    int p = sp;
    const float4* src = (const float4*)(x + (size_t)t * DIMSZ);
    float4 v = src[threadIdx.x];
    u32 w0 = pk2bf(v.x, v.y);
    u32 w1 = pk2bf(v.z, v.w);
    uint2* dst = (uint2*)(Xg + (size_t)p * DIMSZ + threadIdx.x * 4);
    *dst = make_uint2(w0, w1);
}

// ---------------- weight transpose+convert: fp32 [E][K][N] -> bf16 [E][N][K] ----------------
// 64x64 tiles via LDS (u32 = packed bf16 k-pair). Coalesced reads (256B rows) and
// coalesced 16B writes. HBM-bound pass (~384 MB total for W1+W2).
__global__ __launch_bounds__(256) void k_wt(const float* __restrict__ W1,
                                            const float* __restrict__ W2,
                                            u16* __restrict__ W1T,
                                            u16* __restrict__ W2T) {
    int bid = blockIdx.x;
    const float* src;
    u16* dst;
    int K, N, kt, nt;
    if (bid < 8192) {            // W1: per e, tiles = (1024/64)*(4096/64) = 16*64
        int e = bid >> 10, t = bid & 1023;
        kt = t >> 6; nt = t & 63;
        src = W1 + (size_t)e * 1024 * 4096;
        dst = W1T + (size_t)e * 4096 * 1024;
        K = 1024; N = 4096;
    } else {                     // W2: per e, tiles = (4096/64)*(1024/64) = 64*16
        int b = bid - 8192;
        int e = b >> 10, t = b & 1023;
        kt = t >> 4; nt = t & 15;
        src = W2 + (size_t)e * 4096 * 1024;
        dst = W2T + (size_t)e * 1024 * 4096;
        K = 4096; N = 1024;
    }
    __shared__ u32 T[32][65];    // [k-pair][n], u32 = (bf16(k even), bf16(k odd))
    int tid = threadIdx.x;
#pragma unroll
    for (int pass = 0; pass < 2; pass++) {
        int kp = (tid >> 4) + pass * 16;          // k-pair 0..31
        int nc = (tid & 15) * 4;
        const float* r0 = src + (size_t)(kt * 64 + 2 * kp) * N + nt * 64 + nc;
        float4 a = *(const float4*)r0;
        float4 b = *(const float4*)(r0 + N);
        T[kp][nc + 0] = pk2bf(a.x, b.x);
        T[kp][nc + 1] = pk2bf(a.y, b.y);
        T[kp][nc + 2] = pk2bf(a.z, b.z);
        T[kp][nc + 3] = pk2bf(a.w, b.w);
    }
    __syncthreads();
    int n = tid >> 2;                             // out row 0..63
    int sb = (tid & 3) * 8;                       // u32-slot base
    u16* orow = dst + (size_t)(nt * 64 + n) * K + kt * 64;
#pragma unroll
    for (int p = 0; p < 2; p++) {
        int s = sb + p * 4;                       // covers k = 2s .. 2s+7
        uint4 w = make_uint4(T[s][n], T[s + 1][n], T[s + 2][n], T[s + 3][n]);
        *(uint4*)(orow + 2 * s) = w;
    }
}

// ---------------- grouped GEMM, m97-structure: 128x128 tile, BK=32, 4 waves ----------------
// BOTH operands bf16 in HBM, staged via global_load_lds (linear LDS dest, source
// 16B-granule pre-swizzled by (row&3) — rule #21). 16KB LDS, single-buffered,
// 2 barriers/iter (m97-verified shape, 874 TF class). 4 blocks/CU.
// Wt: bf16 [E][NDIM][KDIM] (pre-transposed weights).
// KSPLIT: split K into KSPLIT slices; EPI==2 accumulates via atomicAdd (out pre-zeroed),
// bias added by slice ks==0 only.
template <int KDIM, int NDIM, int EPI, int KSPLIT>
__global__ __launch_bounds__(256, 4) void k_gemm(const u16* __restrict__ A,
                                                 const u16* __restrict__ Wt,
                                                 const float* __restrict__ biasAll,
                                                 const int* __restrict__ counts,
                                                 const int* __restrict__ offs,
                                                 const int* __restrict__ perm,
                                                 u16* __restrict__ Hout,
                                                 float* __restrict__ Fout) {
    constexpr int NT = NDIM / 128;
    constexpr int NWG = RT_MAX * NT * KSPLIT;   // 1280 for both instantiations
    constexpr int CPX = NWG / 8;
    constexpr int KL = KDIM / KSPLIT;           // K per slice
    constexpr int NKL = KL / 32;                // 32 iters for both
    int bid = blockIdx.x;
    int wid = (bid & 7) * CPX + (bid >> 3);     // bijective XCD swizzle
    int x = wid % RT_MAX;                        // row-tile (fastest -> same XCD shares B panel)
    int rest = wid / RT_MAX;
    int ks = rest % KSPLIT;
    int n0 = (rest / KSPLIT) * 128;
    int kbase = ks * KL;

    // map x -> (expert, local row tile)
    int e = -1, lrt = 0, a0 = 0;
#pragma unroll
    for (int i = 0; i < NE; i++) {
        int rt = (counts[i] + 127) >> 7;
        if (e < 0 && x < a0 + rt) { e = i; lrt = x - a0; }
        a0 += rt;
    }
    if (e < 0) return;
    int row0 = offs[e] + lrt * 128;
    int nrows = offs[e] + counts[e] - row0;
    if (nrows > 128) nrows = 128;

    __shared__ alignas(16) u16 As[128][32];   // 8KB, 64B rows, granule-swizzled
    __shared__ alignas(16) u16 Bs[128][32];   // 8KB

    int tid = threadIdx.x;
    int lane = tid & 63;
    int wave = tid >> 6;
    int wr = wave >> 1, wc = wave & 1;

    // staging: granule g = p*256+tid -> LDS row r=g>>2, slot g&3 (16B granules).
    // source holds global k-granule (slot ^ (r&3)) so LDS[r][q] = global granule q^(r&3).
    const u16* srcA[2];
    const u16* srcB[2];
#pragma unroll
    for (int p = 0; p < 2; p++) {
        int g = p * 256 + tid;
        int r = g >> 2, slot = g & 3;
        int rc = r < nrows ? r : nrows - 1;
        int kg = (slot ^ (r & 3)) * 8;
        srcA[p] = A + (size_t)(row0 + rc) * KDIM + kbase + kg;
        srcB[p] = Wt + (size_t)e * NDIM * KDIM + (size_t)(n0 + r) * KDIM + kbase + kg;
    }

    f32x4 acc[4][4] = {};
    int fr = lane & 15, fc = lane >> 4;

    for (int kk = 0; kk < NKL; kk++) {
#pragma unroll
        for (int p = 0; p < 2; p++) {
            __builtin_amdgcn_global_load_lds(
                (const __attribute__((address_space(1))) void*)(srcA[p] + kk * 32),
                (__attribute__((address_space(3))) void*)((u16*)&As[0][0] + (p * 256 + wave * 64) * 8),
                16, 0, 0);
            __builtin_amdgcn_global_load_lds(
                (const __attribute__((address_space(1))) void*)(srcB[p] + kk * 32),
                (__attribute__((address_space(3))) void*)((u16*)&Bs[0][0] + (p * 256 + wave * 64) * 8),
                16, 0, 0);
        }
        __syncthreads();   // drains vmcnt(0) -> tile resident
        bf16x8 af[4], bfr[4];
#pragma unroll
        for (int m = 0; m < 4; m++) {
            int r = wr * 64 + m * 16 + fr;
            af[m] = *(const bf16x8*)&As[r][(fc ^ (r & 3)) * 8];
        }
#pragma unroll
        for (int n = 0; n < 4; n++) {
            int N = wc * 64 + n * 16 + fr;
            bfr[n] = *(const bf16x8*)&Bs[N][(fc ^ (N & 3)) * 8];
        }
#pragma unroll
        for (int m = 0; m < 4; m++)
#pragma unroll
            for (int n = 0; n < 4; n++)
                acc[m][n] = __builtin_amdgcn_mfma_f32_16x16x32_bf16(af[m], bfr[n], acc[m][n], 0, 0, 0);
        __syncthreads();   // all reads done before next overwrite
    }

    // epilogue (C/D layout: col = lane&15, row = (lane>>4)*4 + j)
    int cb = lane & 15;
    int rq = lane >> 4;
#pragma unroll
    for (int m = 0; m < 4; m++) {
        int rbase = wr * 64 + m * 16 + rq * 4;
#pragma unroll
        for (int n = 0; n < 4; n++) {
            int col = n0 + wc * 64 + n * 16 + cb;
            float bias = (EPI == 2 && ks != 0) ? 0.f : biasAll[(size_t)e * NDIM + col];
#pragma unroll
            for (int j = 0; j < 4; j++) {
                int r = rbase + j;
                if (r < nrows) {
                    float v = acc[m][n][j] + bias;
                    int p = row0 + r;
                    if (EPI == 1) {
                        float g = 0.5f * v * (1.0f + erff(v * 0.70710678118654752f));
                        Hout[(size_t)p * NDIM + col] = f2bf(g);
                    } else {
                        int trow = perm[p];
                        atomicAdd(&Fout[(size_t)trow * NDIM + col], v);
                    }
                }
            }
        }
    }
}

// ================= FALLBACK (R7 path, fp32 weights reg-staged) =================
template <int KDIM, int NDIM, int EPI>
__global__ __launch_bounds__(256) void k_gemm_rs(const u16* __restrict__ A,
                                                 const float* __restrict__ Ball,
                                                 const float* __restrict__ biasAll,
                                                 const int* __restrict__ counts,
                                                 const int* __restrict__ offs,
                                                 const int* __restrict__ perm,
                                                 u16* __restrict__ Hout,
                                                 float* __restrict__ Fout) {
#define S8(r) ((((r) ^ ((r) >> 3))) & 7)
    constexpr int NT = NDIM / 128;
    constexpr int NWG = RT_MAX * NT;
    constexpr int CPX = NWG / 8;
    constexpr int NK = KDIM / 64;
    int bid = blockIdx.x;
    int wid = (bid & 7) * CPX + (bid >> 3);
    int x = wid % RT_MAX;
    int n0 = (wid / RT_MAX) * 128;

    int e = -1, lrt = 0, a0 = 0;
#pragma unroll
    for (int i = 0; i < NE; i++) {
        int rt = (counts[i] + 127) >> 7;
        if (e < 0 && x < a0 + rt) { e = i; lrt = x - a0; }
        a0 += rt;
    }
    if (e < 0) return;
    int row0 = offs[e] + lrt * 128;
    int nrows = offs[e] + counts[e] - row0;
    if (nrows > 128) nrows = 128;

    __shared__ alignas(16) u16 Asb[3][128][64];
    __shared__ alignas(16) u16 Bsb[2][128][64];

    int tid = threadIdx.x;
    int lane = tid & 63;
    int wave = tid >> 6;
    int wr = wave >> 1, wc = wave & 1;

    const u16* srcA[4];
#pragma unroll
    for (int p = 0; p < 4; p++) {
        int g = p * 256 + tid;
        int r = g >> 3, slot = g & 7;
        int rc = r < nrows ? r : nrows - 1;
        srcA[p] = A + (size_t)(row0 + rc) * KDIM + ((slot ^ S8(r)) * 8);
    }
    int bn4 = (tid & 31) * 4;
    int bkb = tid >> 5;
    const float* srcB = Ball + (size_t)e * KDIM * NDIM + (size_t)(bkb * 8) * NDIM + n0 + bn4;

    f32x4 acc[4][4] = {};
    int fr = lane & 15, fc = lane >> 4;

    float4 breg[8];
    u16 *Ar = &Asb[0][0][0], *An = &Asb[1][0][0], *Aw = &Asb[2][0][0];
    u16 *Br = &Bsb[0][0][0], *Bw = &Bsb[1][0][0];

#define LOAD_B(KT)                                                              \
    {                                                                           \
        const float* bp = srcB + (size_t)(KT) * 64 * NDIM;                      \
        _Pragma("unroll")                                                       \
        for (int j = 0; j < 8; j++) breg[j] = *(const float4*)(bp + (size_t)j * NDIM); \
    }
#define STAGE_A(DST, KT)                                                        \
    {                                                                           \
        _Pragma("unroll")                                                       \
        for (int p = 0; p < 4; p++) {                                           \
            __builtin_amdgcn_global_load_lds(                                   \
                (const __attribute__((address_space(1))) void*)(srcA[p] + (KT) * 64), \
                (__attribute__((address_space(3))) void*)((DST) + (p * 256 + wave * 64) * 8), \
                16, 0, 0);                                                      \
        }                                                                       \
    }
#define WRITE_B(DST)                                                            \
    {                                                                           \
        const float* vf = (const float*)breg;                                   \
        _Pragma("unroll")                                                       \
        for (int i = 0; i < 4; i++) {                                           \
            int N = bn4 + i;                                                    \
            u32 w0 = pk2bf(vf[0 + i],  vf[4 + i]);                              \
            u32 w1 = pk2bf(vf[8 + i],  vf[12 + i]);                             \
            u32 w2 = pk2bf(vf[16 + i], vf[20 + i]);                             \
            u32 w3 = pk2bf(vf[24 + i], vf[28 + i]);                             \
            u32 off = (u32)(bkb * 16) ^ (u32)(S8(N) << 4);                      \
            *(uint4*)((char*)(DST) + N * 128 + off) = make_uint4(w0, w1, w2, w3); \
        }                                                                       \
    }
#define COMPUTE()                                                               \
    {                                                                           \
        _Pragma("unroll")                                                       \
        for (int k2 = 0; k2 < 2; k2++) {                                        \
            bf16x8 af[4], bfr[4];                                               \
            _Pragma("unroll")                                                   \
            for (int m = 0; m < 4; m++) {                                       \
                int r = wr * 64 + m * 16 + fr;                                  \
                u32 off = (u32)(k2 * 64 + fc * 16) ^ (u32)(S8(r) << 4);         \
                af[m] = *(const bf16x8*)((const char*)Ar + r * 128 + off);      \
            }                                                                   \
            _Pragma("unroll")                                                   \
            for (int n = 0; n < 4; n++) {                                       \
                int N = wc * 64 + n * 16 + fr;                                  \
                u32 off = (u32)(k2 * 64 + fc * 16) ^ (u32)(S8(N) << 4);         \
                bfr[n] = *(const bf16x8*)((const char*)Br + N * 128 + off);     \
            }                                                                   \
            _Pragma("unroll")                                                   \
            for (int m = 0; m < 4; m++)                                         \
                _Pragma("unroll")                                               \
                for (int n = 0; n < 4; n++)                                     \
                    acc[m][n] = __builtin_amdgcn_mfma_f32_16x16x32_bf16(af[m], bfr[n], acc[m][n], 0, 0, 0); \
        }                                                                       \
    }
#define WAITV(N) asm volatile("s_waitcnt vmcnt(" #N ")" ::: "memory")
#define WAITL()  asm volatile("s_waitcnt lgkmcnt(0)" ::: "memory")
#define BAR()    __builtin_amdgcn_s_barrier()

    LOAD_B(0);
    STAGE_A(Ar, 0);
    WAITV(4);
    WRITE_B(Br);
    LOAD_B(1);
    STAGE_A(An, 1);
    WAITV(12);
    WAITL();
    BAR();

    for (int kk = 0; kk < NK - 2; kk++) {
        COMPUTE();
        WAITV(4);
        WRITE_B(Bw);
        LOAD_B(kk + 2);
        STAGE_A(Aw, kk + 2);
        WAITV(12);
        WAITL();
        BAR();
        u16* t = Ar; Ar = An; An = Aw; Aw = t;
        t = Br; Br = Bw; Bw = t;
    }
    COMPUTE();
    WAITV(4);
    WRITE_B(Bw);
    WAITV(0);
    WAITL();
    BAR();
    { u16* t = Ar; Ar = An; An = Aw; Aw = t; t = Br; Br = Bw; Bw = t; }
    COMPUTE();

#undef LOAD_B
#undef STAGE_A
#undef WRITE_B
#undef COMPUTE
#undef WAITV
#undef WAITL
#undef BAR
#undef S8

    int cb = lane & 15;
    int rq = lane >> 4;
#pragma unroll
    for (int m = 0; m < 4; m++) {
        int rbase = wr * 64 + m * 16 + rq * 4;
#pragma unroll
        for (int n = 0; n < 4; n++) {
            int col = n0 + wc * 64 + n * 16 + cb;
            float bias = biasAll[(size_t)e * NDIM + col];
#pragma unroll
            for (int j = 0; j < 4; j++) {
                int r = rbase + j;
                if (r < nrows) {
                    float v = acc[m][n][j] + bias;
                    int p = row0 + r;
                    if (EPI == 1) {
                        float g = 0.5f * v * (1.0f + erff(v * 0.70710678118654752f));
                        Hout[(size_t)p * NDIM + col] = f2bf(g);
                    } else {
                        int trow = perm[p];
                        Fout[(size_t)trow * NDIM + col] = v;
                    }
                }
            }
        }
    }
}

extern "C" void kernel_launch(void* const* d_in, const int* in_sizes, int n_in,
                              void* d_out, int out_size, void* d_ws, size_t ws_size,
                              hipStream_t stream) {
    const float* x  = (const float*)d_in[0];
    const float* Wg = (const float*)d_in[1];
    const float* W1 = (const float*)d_in[2];
    const float* b1 = (const float*)d_in[3];
    const float* W2 = (const float*)d_in[4];
    const float* b2 = (const float*)d_in[5];
    float* out = (float*)d_out;

    char* ws = (char*)d_ws;
    int* ids    = (int*)(ws + 0);          // 16384 B
    int* counts = (int*)(ws + 16384);      // 32 B
    int* offs   = (int*)(ws + 16448);      // 32 B
    int* cursor = (int*)(ws + 16512);      // 32 B
    int* perm   = (int*)(ws + 16576);      // 16384 B

    // new-path layout (168.1 MiB)
    u16* XgN  = (u16*)(ws + 65536);                      // 8 MiB
    u16* HN   = (u16*)(ws + 65536 + 8388608);            // 32 MiB
    u16* W1T  = (u16*)(ws + 65536 + 8388608 + 33554432); // 64 MiB
    u16* W2T  = (u16*)(ws + 65536 + 8388608 + 33554432 + 67108864); // 64 MiB
    const size_t NEED = 65536ull + 8388608 + 33554432 + 67108864 + 67108864;

    k_init<<<dim3(1), dim3(64), 0, stream>>>(counts, cursor);
    k_router<<<dim3(NTOK / 4), dim3(256), 0, stream>>>(x, Wg, ids, counts);
    k_scan<<<dim3(1), dim3(64), 0, stream>>>(counts, offs);

    if (ws_size >= NEED) {
        k_gather<<<dim3(NTOK), dim3(256), 0, stream>>>(x, ids, offs, cursor, perm, XgN);
        k_wt<<<dim3(16384), dim3(256), 0, stream>>>(W1, W2, W1T, W2T);
        k_zero<<<dim3(NTOK * DIMSZ / 1024), dim3(256), 0, stream>>>(out);
        k_gemm<DIMSZ, HID, 1, 1><<<dim3(RT_MAX * (HID / 128)), dim3(256), 0, stream>>>(
            XgN, W1T, b1, counts, offs, perm, HN, (float*)nullptr);
        k_gemm<HID, DIMSZ, 2, 4><<<dim3(RT_MAX * (DIMSZ / 128) * 4), dim3(256), 0, stream>>>(
            HN, W2T, b2, counts, offs, perm, (u16*)nullptr, out);
    } else {
        // fallback: R7 path (fp32 weights, reg-staged B)
        u16* Xg = (u16*)(ws + 33024);
        u16* H  = (u16*)(ws + 33024 + 8388608);
        k_gather<<<dim3(NTOK), dim3(256), 0, stream>>>(x, ids, offs, cursor, perm, Xg);
        k_gemm_rs<DIMSZ, HID, 1><<<dim3(RT_MAX * (HID / 128)), dim3(256), 0, stream>>>(
            Xg, W1, b1, counts, offs, perm, H, (float*)nullptr);
        k_gemm_rs<HID, DIMSZ, 2><<<dim3(RT_MAX * (DIMSZ / 128)), dim3(256), 0, stream>>>(
            H, W2, b2, counts, offs, perm, (u16*)nullptr, out);
    }
}

// Round 9
// 365.657 us; speedup vs baseline: 1.1181x; 1.1181x over previous
//
#include <hip/hip_runtime.h>
#include <hip/hip_bf16.h>
#include <math.h>

#define NTOK 4096
#define DIMSZ 1024
#define HID 4096
#define NE 8
#define RT_MAX 40   // max sum over experts of ceil(count/128) is 39; pad to 40

typedef unsigned short u16;
typedef unsigned int u32;
typedef __attribute__((ext_vector_type(8))) short bf16x8;
typedef __attribute__((ext_vector_type(4))) float f32x4;

// granule swizzle: row r, physical 16B-slot q holds global k-granule q ^ SWZ(r).
// SWZ = (r>>1)&3 spreads 16 consecutive rows' slot-q reads over all 8 bank-quads
// (r&3 left rows {0,4,8,12} on the same quad -> 4-way conflict, R8's 4.7M cycles).
#define SWZ(r) (((r) >> 1) & 3)

static __device__ __forceinline__ u16 f2bf(float f) {
    u32 u = __float_as_uint(f);
    u32 r = u + 0x7fffu + ((u >> 16) & 1u);   // round-to-nearest-even
    return (u16)(r >> 16);
}

static __device__ __forceinline__ u32 pk2bf(float lo, float hi) {
    __hip_bfloat162 h = __float22bfloat162_rn(make_float2(lo, hi));
    return *(u32*)&h;
}

// ---------------- init: zero counts + cursor ----------------
__global__ void k_init(int* counts, int* cursor) {
    if (threadIdx.x < NE) { counts[threadIdx.x] = 0; cursor[threadIdx.x] = 0; }
}

// ---------------- zero d_out (for GEMM2 K-split atomics) ----------------
__global__ void k_zero(float* p) {
    int i = blockIdx.x * 1024 + threadIdx.x * 4;
    *(float4*)(p + i) = make_float4(0.f, 0.f, 0.f, 0.f);
}

// ---------------- router: fp32 argmax over 8 experts ----------------
__global__ __launch_bounds__(256) void k_router(const float* __restrict__ x,
                                                const float* __restrict__ Wg,
                                                int* __restrict__ ids,
                                                int* __restrict__ counts) {
    int wave = threadIdx.x >> 6;
    int lane = threadIdx.x & 63;
    int t = blockIdx.x * 4 + wave;

    const float4* xr = (const float4*)(x + (size_t)t * DIMSZ);
    float4 xv[4];
#pragma unroll
    for (int j = 0; j < 4; j++) xv[j] = xr[j * 64 + lane];

    float s[NE];
#pragma unroll
    for (int e = 0; e < NE; e++) {
        const float4* wr = (const float4*)(Wg + (size_t)e * DIMSZ);
        float p = 0.f;
#pragma unroll
        for (int j = 0; j < 4; j++) {
            float4 w = wr[j * 64 + lane];
            p += xv[j].x * w.x + xv[j].y * w.y + xv[j].z * w.z + xv[j].w * w.w;
        }
#pragma unroll
        for (int m = 32; m >= 1; m >>= 1) p += __shfl_xor(p, m, 64);
        s[e] = p;
    }
    if (lane == 0) {
        int best = 0;
#pragma unroll
        for (int e = 1; e < NE; e++) if (s[e] > s[best]) best = e;  // first-max tiebreak
        ids[t] = best;
        atomicAdd(&counts[best], 1);
    }
}

// ---------------- scan: exclusive prefix over 8 counts ----------------
__global__ void k_scan(const int* __restrict__ counts, int* __restrict__ offs) {
    if (threadIdx.x == 0) {
        int a = 0;
        for (int e = 0; e < NE; e++) { offs[e] = a; a += counts[e]; }
    }
}

// ---------------- gather: build perm + bf16-convert x into grouped Xg ----------------
__global__ __launch_bounds__(256) void k_gather(const float* __restrict__ x,
                                                const int* __restrict__ ids,
                                                const int* __restrict__ offs,
                                                int* __restrict__ cursor,
                                                int* __restrict__ perm,
                                                u16* __restrict__ Xg) {
    int t = blockIdx.x;
    __shared__ int sp;
    if (threadIdx.x == 0) {
        int e = ids[t];
        int p = offs[e] + atomicAdd(&cursor[e], 1);
        perm[p] = t;
        sp = p;
    }
    __syncthreads();
    int p = sp;
    const float4* src = (const float4*)(x + (size_t)t * DIMSZ);
    float4 v = src[threadIdx.x];
    u32 w0 = pk2bf(v.x, v.y);
    u32 w1 = pk2bf(v.z, v.w);
    uint2* dst = (uint2*)(Xg + (size_t)p * DIMSZ + threadIdx.x * 4);
    *dst = make_uint2(w0, w1);
}

// ---------------- weight transpose+convert: fp32 [E][K][N] -> bf16 [E][N][K] ----------------
__global__ __launch_bounds__(256) void k_wt(const float* __restrict__ W1,
                                            const float* __restrict__ W2,
                                            u16* __restrict__ W1T,
                                            u16* __restrict__ W2T) {
    int bid = blockIdx.x;
    const float* src;
    u16* dst;
    int K, N, kt, nt;
    if (bid < 8192) {            // W1: per e, tiles = (1024/64)*(4096/64) = 16*64
        int e = bid >> 10, t = bid & 1023;
        kt = t >> 6; nt = t & 63;
        src = W1 + (size_t)e * 1024 * 4096;
        dst = W1T + (size_t)e * 4096 * 1024;
        K = 1024; N = 4096;
    } else {                     // W2: per e, tiles = (4096/64)*(1024/64) = 64*16
        int b = bid - 8192;
        int e = b >> 10, t = b & 1023;
        kt = t >> 4; nt = t & 15;
        src = W2 + (size_t)e * 4096 * 1024;
        dst = W2T + (size_t)e * 1024 * 4096;
        K = 4096; N = 1024;
    }
    __shared__ u32 T[32][65];    // [k-pair][n], u32 = (bf16(k even), bf16(k odd))
    int tid = threadIdx.x;
#pragma unroll
    for (int pass = 0; pass < 2; pass++) {
        int kp = (tid >> 4) + pass * 16;          // k-pair 0..31
        int nc = (tid & 15) * 4;
        const float* r0 = src + (size_t)(kt * 64 + 2 * kp) * N + nt * 64 + nc;
        float4 a = *(const float4*)r0;
        float4 b = *(const float4*)(r0 + N);
        T[kp][nc + 0] = pk2bf(a.x, b.x);
        T[kp][nc + 1] = pk2bf(a.y, b.y);
        T[kp][nc + 2] = pk2bf(a.z, b.z);
        T[kp][nc + 3] = pk2bf(a.w, b.w);
    }
    __syncthreads();
    int n = tid >> 2;                             // out row 0..63
    int sb = (tid & 3) * 8;                       // u32-slot base
    u16* orow = dst + (size_t)(nt * 64 + n) * K + kt * 64;
#pragma unroll
    for (int p = 0; p < 2; p++) {
        int s = sb + p * 4;                       // covers k = 2s .. 2s+7
        uint4 w = make_uint4(T[s][n], T[s + 1][n], T[s + 2][n], T[s + 3][n]);
        *(uint4*)(orow + 2 * s) = w;
    }
}

// ---------------- grouped GEMM: 128x128 tile, BK=32, 4 waves ----------------
// Counted-vmcnt pipeline (T3/T4, m201-verified pattern): BOTH operands bf16 via
// global_load_lds into TRIPLE-buffered LDS tiles (48KB -> 3 blocks/CU), prefetch
// distance 2, ONE barrier per K-step, WAITV(4) (never 0) in the main loop.
// WAITV precedes BAR so after the barrier ALL waves' stage(kk) ops have landed.
// Write hazard: STAGE(kk+2) overwrites the buffer read at COMPUTE(kk-1), whose
// ds_reads completed before this iteration's barrier (lgkm waits precede MFMA use).
// Axis order: row-tile SLOW so one XCD chunk = few row-tiles x all n-stripes ->
// the A panel (1.25-2.5MB) stays L2-resident across the whole chunk (R8: 215MB
// FETCH came from A re-streaming with row-tile fast).
template <int KDIM, int NDIM, int EPI, int KSPLIT>
__global__ __launch_bounds__(256, 3) void k_gemm(const u16* __restrict__ A,
                                                 const u16* __restrict__ Wt,
                                                 const float* __restrict__ biasAll,
                                                 const int* __restrict__ counts,
                                                 const int* __restrict__ offs,
                                                 const int* __restrict__ perm,
                                                 u16* __restrict__ Hout,
                                                 float* __restrict__ Fout) {
    constexpr int NT = NDIM / 128;
    constexpr int NREST = NT * KSPLIT;
    constexpr int NWG = RT_MAX * NREST;         // 1280 (G1) / 640 (G2)
    constexpr int CPX = NWG / 8;
    constexpr int KL = KDIM / KSPLIT;
    constexpr int NKL = KL / 32;                // 32 (G1) / 64 (G2)
    int bid = blockIdx.x;
    int wid = (bid & 7) * CPX + (bid >> 3);     // bijective XCD swizzle
    int x = wid / NREST;                         // row-tile (SLOW axis)
    int rest = wid % NREST;
    int ks = rest % KSPLIT;
    int n0 = (rest / KSPLIT) * 128;
    int kbase = ks * KL;

    // map x -> (expert, local row tile)
    int e = -1, lrt = 0, a0 = 0;
#pragma unroll
    for (int i = 0; i < NE; i++) {
        int rt = (counts[i] + 127) >> 7;
        if (e < 0 && x < a0 + rt) { e = i; lrt = x - a0; }
        a0 += rt;
    }
    if (e < 0) return;
    int row0 = offs[e] + lrt * 128;
    int nrows = offs[e] + counts[e] - row0;
    if (nrows > 128) nrows = 128;

    __shared__ alignas(16) u16 Asb[3][128][32];   // 24KB rotating triple buffer
    __shared__ alignas(16) u16 Bsb[3][128][32];   // 24KB

    int tid = threadIdx.x;
    int lane = tid & 63;
    int wave = tid >> 6;
    int wr = wave >> 1, wc = wave & 1;

    // staging: granule g = p*256+tid -> LDS row r=g>>2, slot g&3 (16B granules,
    // linear LDS dest); source holds global k-granule (slot ^ SWZ(r)). (rule #21)
    const u16* srcA[2];
    const u16* srcB[2];
#pragma unroll
    for (int p = 0; p < 2; p++) {
        int g = p * 256 + tid;
        int r = g >> 2, slot = g & 3;
        int rc = r < nrows ? r : nrows - 1;
        int kg = (slot ^ SWZ(r)) * 8;
        srcA[p] = A + (size_t)(row0 + rc) * KDIM + kbase + kg;
        srcB[p] = Wt + (size_t)e * NDIM * KDIM + (size_t)(n0 + r) * KDIM + kbase + kg;
    }

    f32x4 acc[4][4] = {};
    int fr = lane & 15, fc = lane >> 4;

    u16 *A0 = &Asb[0][0][0], *A1 = &Asb[1][0][0], *A2 = &Asb[2][0][0];
    u16 *B0 = &Bsb[0][0][0], *B1 = &Bsb[1][0][0], *B2 = &Bsb[2][0][0];

#define STAGE(AD, BD, KT)                                                       \
    {                                                                           \
        _Pragma("unroll")                                                       \
        for (int p = 0; p < 2; p++) {                                           \
            __builtin_amdgcn_global_load_lds(                                   \
                (const __attribute__((address_space(1))) void*)(srcA[p] + (size_t)(KT) * 32), \
                (__attribute__((address_space(3))) void*)((AD) + (p * 256 + wave * 64) * 8), \
                16, 0, 0);                                                      \
            __builtin_amdgcn_global_load_lds(                                   \
                (const __attribute__((address_space(1))) void*)(srcB[p] + (size_t)(KT) * 32), \
                (__attribute__((address_space(3))) void*)((BD) + (p * 256 + wave * 64) * 8), \
                16, 0, 0);                                                      \
        }                                                                       \
    }

#define COMPUTE(AP, BP)                                                         \
    {                                                                           \
        bf16x8 af[4], bfr[4];                                                   \
        _Pragma("unroll")                                                       \
        for (int m = 0; m < 4; m++) {                                           \
            int r = wr * 64 + m * 16 + fr;                                      \
            af[m] = *(const bf16x8*)((AP) + r * 32 + (fc ^ SWZ(r)) * 8);        \
        }                                                                       \
        _Pragma("unroll")                                                       \
        for (int n = 0; n < 4; n++) {                                           \
            int N = wc * 64 + n * 16 + fr;                                      \
            bfr[n] = *(const bf16x8*)((BP) + N * 32 + (fc ^ SWZ(N)) * 8);       \
        }                                                                       \
        _Pragma("unroll")                                                       \
        for (int m = 0; m < 4; m++)                                             \
            _Pragma("unroll")                                                   \
            for (int n = 0; n < 4; n++)                                         \
                acc[m][n] = __builtin_amdgcn_mfma_f32_16x16x32_bf16(af[m], bfr[n], acc[m][n], 0, 0, 0); \
    }

#define WAITV(N) asm volatile("s_waitcnt vmcnt(" #N ")" ::: "memory")
#define BAR()    __builtin_amdgcn_s_barrier()
#define SBAR()   __builtin_amdgcn_sched_barrier(0)

    // prologue: issue tiles 0 and 1 (4 vmem ops each)
    STAGE(A0, B0, 0);
    STAGE(A1, B1, 1);

    // main loop: kk = 0 .. NKL-3
    for (int kk = 0; kk < NKL - 2; kk++) {
        WAITV(4);              // stage(kk) landed for THIS wave (stage(kk+1) in flight)
        BAR();                 // -> landed for ALL waves
        SBAR();
        STAGE(A2, B2, kk + 2); // overwrites buffer last read at COMPUTE(kk-1)
        COMPUTE(A0, B0);       // tile kk
        u16* t;
        t = A0; A0 = A1; A1 = A2; A2 = t;
        t = B0; B0 = B1; B1 = B2; B2 = t;
    }
    // iter NKL-2 (no more staging)
    WAITV(4);
    BAR();
    SBAR();
    COMPUTE(A0, B0);
    // iter NKL-1 (drain last stage)
    WAITV(0);
    BAR();
    SBAR();
    COMPUTE(A1, B1);

#undef STAGE
#undef COMPUTE
#undef WAITV
#undef BAR
#undef SBAR

    // epilogue (C/D layout: col = lane&15, row = (lane>>4)*4 + j)
    int cb = lane & 15;
    int rq = lane >> 4;
#pragma unroll
    for (int m = 0; m < 4; m++) {
        int rbase = wr * 64 + m * 16 + rq * 4;
#pragma unroll
        for (int n = 0; n < 4; n++) {
            int col = n0 + wc * 64 + n * 16 + cb;
            float bias = (EPI == 2 && ks != 0) ? 0.f : biasAll[(size_t)e * NDIM + col];
#pragma unroll
            for (int j = 0; j < 4; j++) {
                int r = rbase + j;
                if (r < nrows) {
                    float v = acc[m][n][j] + bias;
                    int p = row0 + r;
                    if (EPI == 1) {
                        float g = 0.5f * v * (1.0f + erff(v * 0.70710678118654752f));
                        Hout[(size_t)p * NDIM + col] = f2bf(g);
                    } else {
                        int trow = perm[p];
                        atomicAdd(&Fout[(size_t)trow * NDIM + col], v);
                    }
                }
            }
        }
    }
}

extern "C" void kernel_launch(void* const* d_in, const int* in_sizes, int n_in,
                              void* d_out, int out_size, void* d_ws, size_t ws_size,
                              hipStream_t stream) {
    const float* x  = (const float*)d_in[0];
    const float* Wg = (const float*)d_in[1];
    const float* W1 = (const float*)d_in[2];
    const float* b1 = (const float*)d_in[3];
    const float* W2 = (const float*)d_in[4];
    const float* b2 = (const float*)d_in[5];
    float* out = (float*)d_out;

    char* ws = (char*)d_ws;
    int* ids    = (int*)(ws + 0);          // 16384 B
    int* counts = (int*)(ws + 16384);      // 32 B
    int* offs   = (int*)(ws + 16448);      // 32 B
    int* cursor = (int*)(ws + 16512);      // 32 B
    int* perm   = (int*)(ws + 16576);      // 16384 B

    u16* Xg   = (u16*)(ws + 65536);                      // 8 MiB
    u16* H    = (u16*)(ws + 65536 + 8388608);            // 32 MiB
    u16* W1T  = (u16*)(ws + 65536 + 8388608 + 33554432); // 64 MiB
    u16* W2T  = (u16*)(ws + 65536 + 8388608 + 33554432 + 67108864); // 64 MiB

    k_init<<<dim3(1), dim3(64), 0, stream>>>(counts, cursor);
    k_router<<<dim3(NTOK / 4), dim3(256), 0, stream>>>(x, Wg, ids, counts);
    k_scan<<<dim3(1), dim3(64), 0, stream>>>(counts, offs);
    k_gather<<<dim3(NTOK), dim3(256), 0, stream>>>(x, ids, offs, cursor, perm, Xg);
    k_wt<<<dim3(16384), dim3(256), 0, stream>>>(W1, W2, W1T, W2T);
    k_zero<<<dim3(NTOK * DIMSZ / 1024), dim3(256), 0, stream>>>(out);
    k_gemm<DIMSZ, HID, 1, 1><<<dim3(RT_MAX * (HID / 128)), dim3(256), 0, stream>>>(
        Xg, W1T, b1, counts, offs, perm, H, (float*)nullptr);
    k_gemm<HID, DIMSZ, 2, 2><<<dim3(RT_MAX * (DIMSZ / 128) * 2), dim3(256), 0, stream>>>(
        H, W2T, b2, counts, offs, perm, (u16*)nullptr, out);
}